// Round 1
// baseline (2826.512 us; speedup 1.0000x reference)
//
#include <hip/hip_runtime.h>
#include <math.h>

#define BB 8
#define NN 12800
#define FF 256
#define DDIM 128
#define NBINS 100
#define BSIZE 128
#define NROT 50
#define NIDS 199
#define PTS (BB*NN)            // 102400

// ---- workspace layout (bytes) ----
#define OFF_R0   ((size_t)0)            // 104857600 : xd (early, first 52MB) then FH/T2/out1
#define OFF_R1   ((size_t)104857600)    // 104857600 : T / out0
#define OFF_DM   ((size_t)209715200)    // 52428800
#define OFF_NORM ((size_t)262144000)    // 409600
#define OFF_MF   ((size_t)262553600)    // 409600
#define OFF_BIN  ((size_t)262963200)    // 409600 (int)
#define OFF_FLAT ((size_t)263372800)    // 409600 (int)
#define OFF_MSKI ((size_t)263782400)    // 409600 (int)
#define OFF_HIST ((size_t)264192000)    // 636800 (int)
#define OFF_OFFS ((size_t)264828800)    // 636800 (int)
#define OFF_FLAG ((size_t)265465600)    // 64
#define HISTBYTES (8*100*199*4)

// ---------- mask dtype sniffing ----------
__global__ void k_maskflag(const int* mi, int* flag) {
    __shared__ int notInt, notFloat;
    if (threadIdx.x == 0) { notInt = 0; notFloat = 0; }
    __syncthreads();
    int v = mi[threadIdx.x];
    if (v != 0 && v != 1) atomicOr(&notInt, 1);
    if (v != 0 && v != 0x3F800000) atomicOr(&notFloat, 1);
    __syncthreads();
    if (threadIdx.x == 0) {
        // 0 = int32 0/1, 2 = float 0/1, 1 = bytes
        flag[0] = (!notInt) ? 0 : ((!notFloat) ? 2 : 1);
    }
}

__global__ void k_masknorm(const void* msk, const int* flag, int* mski) {
    int i = blockIdx.x * blockDim.x + threadIdx.x;
    if (i >= PTS) return;
    int f = flag[0];
    int v;
    if (f == 0)      v = ((const int*)msk)[i] != 0;
    else if (f == 2) v = ((const float*)msk)[i] != 0.0f;
    else             v = ((const unsigned char*)msk)[i] != 0;
    mski[i] = v;
}

// ---------- stage 1: LN + FFN + rot + argmax (fp64 chain) ----------
__global__ __launch_bounds__(256) void k_stage1(
    const float* __restrict__ x, const float* __restrict__ g, const float* __restrict__ be,
    const float* __restrict__ w1, const float* __restrict__ b1,
    const float* __restrict__ w2, const float* __restrict__ b2,
    const float* __restrict__ rot, const int* __restrict__ mski,
    float* __restrict__ xn_out, float* __restrict__ xd_out, int* __restrict__ bin_out)
{
    __shared__ double xs[16][FF];
    __shared__ double hs[16][DDIM];
    int tid = threadIdx.x;
    int base = blockIdx.x * 16;

    // phase 0: load + layernorm
    {
        int pl = tid >> 4, t = tid & 15;
        int pt = base + pl;
        const float* xr = x + (size_t)pt * FF;
        double s = 0.0;
        for (int i = t; i < FF; i += 16) { double v = (double)xr[i]; xs[pl][i] = v; s += v; }
        for (int off = 1; off < 16; off <<= 1) s += __shfl_xor(s, off, 16);
        double mu = s * (1.0 / 256.0);
        double s2 = 0.0;
        for (int i = t; i < FF; i += 16) { double d = xs[pl][i] - mu; s2 += d * d; }
        for (int off = 1; off < 16; off <<= 1) s2 += __shfl_xor(s2, off, 16);
        double rs = 1.0 / sqrt(s2 * (1.0 / 256.0) + 1e-6);
        float* xo = xn_out + (size_t)pt * FF;
        for (int i = t; i < FF; i += 16) {
            double v = (xs[pl][i] - mu) * rs * (double)g[i] + (double)be[i];
            xs[pl][i] = v;
            xo[i] = (float)v;
        }
    }
    __syncthreads();
    // phase 1: h = elu(xn @ w1 + b1)
    {
        int j = tid & 127, pg = tid >> 7;
        double acc[8];
        double bj = (double)b1[j];
        #pragma unroll
        for (int r = 0; r < 8; r++) acc[r] = bj;
        for (int k = 0; k < FF; k++) {
            double w = (double)w1[k * DDIM + j];
            #pragma unroll
            for (int r = 0; r < 8; r++) acc[r] += xs[pg * 8 + r][k] * w;
        }
        #pragma unroll
        for (int r = 0; r < 8; r++) {
            double h = acc[r];
            hs[pg * 8 + r][j] = (h > 0.0) ? h : expm1(h);
        }
    }
    __syncthreads();
    // phase 2: xd = h @ w2 + b2  (store f64 into xs[:][0:128] and fp32 global)
    {
        int j = tid & 127, pg = tid >> 7;
        double acc[8];
        double bj = (double)b2[j];
        #pragma unroll
        for (int r = 0; r < 8; r++) acc[r] = bj;
        for (int k = 0; k < DDIM; k++) {
            double w = (double)w2[k * DDIM + j];
            #pragma unroll
            for (int r = 0; r < 8; r++) acc[r] += hs[pg * 8 + r][k] * w;
        }
        __syncthreads();   // everyone done reading hs and old xs before overwrite
        #pragma unroll
        for (int r = 0; r < 8; r++) {
            int p = pg * 8 + r;
            xs[p][j] = acc[r];
            xd_out[(size_t)(base + p) * DDIM + j] = (float)acc[r];
        }
    }
    __syncthreads();
    // phase 3: mul = xd @ rot[:, :50]; argmax over [mul, -mul]
    {
        int c = tid & 63, wv = tid >> 6;
        for (int r = 0; r < 4; r++) {
            int p = wv * 4 + r;
            double v; int idx;
            if (c < NROT) {
                double m = 0.0;
                for (int k = 0; k < DDIM; k++) m += xs[p][k] * (double)rot[k * 100 + c];
                if (m >= 0.0) { v = m; idx = c; } else { v = -m; idx = 50 + c; }
            } else { v = -1e300; idx = 1 << 29; }
            #pragma unroll
            for (int off = 1; off < 64; off <<= 1) {
                double ov = __shfl_xor(v, off, 64);
                int oi = __shfl_xor(idx, off, 64);
                if (ov > v || (ov == v && oi < idx)) { v = ov; idx = oi; }
            }
            if (c == 0) {
                int pt = base + p;
                bin_out[pt] = idx + (mski[pt] ? 0 : (NBINS - 1));
            }
        }
    }
}

// ---------- binning: stable counting sort ----------
__global__ void k_count(const int* __restrict__ bin, int* __restrict__ hist) {
    int c = blockIdx.x % 100, b = blockIdx.x / 100;
    int t = threadIdx.x;
    int v = bin[b * NN + c * BSIZE + t];
    atomicAdd(&hist[(b * 100 + c) * NIDS + v], 1);
}

__global__ void k_offsets(const int* __restrict__ hist, int* __restrict__ offs) {
    __shared__ int tot[NIDS];
    __shared__ int start[NIDS];
    int b = blockIdx.x, v = threadIdx.x;
    if (v < NIDS) {
        int s = 0;
        for (int c = 0; c < 100; c++) s += hist[(b * 100 + c) * NIDS + v];
        tot[v] = s;
    }
    __syncthreads();
    if (threadIdx.x == 0) {
        int run = 0;
        for (int i = 0; i < NIDS; i++) { start[i] = run; run += tot[i]; }
    }
    __syncthreads();
    if (v < NIDS) {
        int run = start[v];
        for (int c = 0; c < 100; c++) {
            offs[(b * 100 + c) * NIDS + v] = run;
            run += hist[(b * 100 + c) * NIDS + v];
        }
    }
}

__global__ void k_scatter(const int* __restrict__ bin, const int* __restrict__ offs,
                          const int* __restrict__ mski, int* __restrict__ flat,
                          float* __restrict__ mf) {
    __shared__ int sv[BSIZE];
    int c = blockIdx.x % 100, b = blockIdx.x / 100;
    int t = threadIdx.x;
    int n = c * BSIZE + t;
    int v = bin[b * NN + n];
    sv[t] = v;
    __syncthreads();
    int rank = 0;
    for (int u = 0; u < t; u++) rank += (sv[u] == v);
    int r = offs[(b * 100 + c) * NIDS + v] + rank;
    flat[b * NN + r] = b * NN + n;          // global row index
    mf[b * NN + r] = mski[b * NN + n] ? 1.0f : 0.0f;
}

// ---------- per-bin pairwise kernel matrix ----------
__global__ __launch_bounds__(256) void k_dm(const float* __restrict__ xd, const int* __restrict__ flat,
                                            const float* __restrict__ mf, float* __restrict__ dm) {
    __shared__ float xt[64 * 128];     // idx(kk,j) = kk*128 + (j ^ (kk&31))
    __shared__ float nal[BSIZE];
    __shared__ float ml[BSIZE];
    int g = blockIdx.x, tid = threadIdx.x;
    int rowbase = g * BSIZE;
    if (tid < BSIZE) ml[tid] = mf[rowbase + tid];
    float acc[64];
    #pragma unroll
    for (int i = 0; i < 64; i++) acc[i] = 0.f;
    float naj = 0.f;
    int h = tid >> 7, j = tid & 127;
    for (int kt = 0; kt < 2; kt++) {
        __syncthreads();
        {
            int gg = tid >> 6, lane = tid & 63;
            for (int it = 0; it < 32; it++) {
                int row = it * 4 + gg;
                int src = flat[rowbase + row];
                float v = xd[(size_t)src * DDIM + kt * 64 + lane];
                xt[lane * 128 + (row ^ (lane & 31))] = v;
            }
        }
        __syncthreads();
        if (tid < BSIZE) {
            for (int kk = 0; kk < 64; kk++) {
                float v = xt[kk * 128 + (tid ^ (kk & 31))];
                naj += v * v;
            }
        }
        for (int kk = 0; kk < 64; kk++) {
            float vj = xt[kk * 128 + (j ^ (kk & 31))];
            #pragma unroll
            for (int rep = 0; rep < 64; rep++) {
                float vi = xt[kk * 128 + ((2 * rep + h) ^ (kk & 31))];
                acc[rep] += vi * vj;
            }
        }
    }
    __syncthreads();
    if (tid < BSIZE) nal[tid] = naj;
    __syncthreads();
    float mj = ml[j];
    for (int rep = 0; rep < 64; rep++) {
        int i = 2 * rep + h;
        float D2 = nal[i] - 2.f * acc[rep] + nal[j];
        float dv = expf(-0.1f * sqrtf(fmaxf(D2, 1e-6f)));
        dv *= ml[i] * mj;
        dm[(size_t)g * 16384 + (size_t)i * 128 + j] = dv;
    }
}

__global__ void k_normk(const float* __restrict__ dm, const float* __restrict__ mf,
                        float* __restrict__ norm) {
    int g = blockIdx.x, r = threadIdx.x;
    const float* row = dm + (size_t)g * 16384 + (size_t)r * 128;
    float s = 0.f;
    for (int jj = 0; jj < 128; jj++) s += row[jj];
    s = fminf(fmaxf(s, 0.f), 1000.f);
    float n = 1.0f / sqrtf(s + 1e-6f);
    norm[g * 128 + r] = n * mf[g * 128 + r];
}

// ---------- GEMM: T[row,c] = norm[row] * sum_k A[srcrow,k]*W[k,c] ----------
__global__ __launch_bounds__(256) void k_proj(const float* __restrict__ Ain, const int* __restrict__ flat,
                                              const float* __restrict__ W, const float* __restrict__ norm,
                                              float* __restrict__ out) {
    __shared__ float As[64][36];
    __shared__ float Ws[32][68];
    int rb = blockIdx.x, cb = blockIdx.y;
    int tid = threadIdx.x;
    int rowbase = rb * 64, cbase = cb * 64;
    int tx = tid & 15, ty = tid >> 4;
    float acc[4][4] = {};
    for (int kb = 0; kb < FF; kb += 32) {
        __syncthreads();
        {
            int row = tid >> 2, col0 = (tid & 3) * 8;
            int src = flat ? flat[rowbase + row] : (rowbase + row);
            const float* ap = Ain + (size_t)src * FF + kb + col0;
            float4 v0 = *(const float4*)ap;
            float4 v1 = *(const float4*)(ap + 4);
            As[row][col0 + 0] = v0.x; As[row][col0 + 1] = v0.y;
            As[row][col0 + 2] = v0.z; As[row][col0 + 3] = v0.w;
            As[row][col0 + 4] = v1.x; As[row][col0 + 5] = v1.y;
            As[row][col0 + 6] = v1.z; As[row][col0 + 7] = v1.w;
        }
        {
            int kk = tid >> 3, cc0 = (tid & 7) * 8;
            const float* wp = W + (size_t)(kb + kk) * FF + cbase + cc0;
            float4 v0 = *(const float4*)wp;
            float4 v1 = *(const float4*)(wp + 4);
            Ws[kk][cc0 + 0] = v0.x; Ws[kk][cc0 + 1] = v0.y;
            Ws[kk][cc0 + 2] = v0.z; Ws[kk][cc0 + 3] = v0.w;
            Ws[kk][cc0 + 4] = v1.x; Ws[kk][cc0 + 5] = v1.y;
            Ws[kk][cc0 + 6] = v1.z; Ws[kk][cc0 + 7] = v1.w;
        }
        __syncthreads();
        for (int kk = 0; kk < 32; kk++) {
            float a[4], bv[4];
            #pragma unroll
            for (int i = 0; i < 4; i++) a[i] = As[ty * 4 + i][kk];
            #pragma unroll
            for (int jj = 0; jj < 4; jj++) bv[jj] = Ws[kk][tx * 4 + jj];
            #pragma unroll
            for (int i = 0; i < 4; i++)
                #pragma unroll
                for (int jj = 0; jj < 4; jj++) acc[i][jj] += a[i] * bv[jj];
        }
    }
    #pragma unroll
    for (int i = 0; i < 4; i++) {
        int row = rowbase + ty * 4 + i;
        float nv = norm[row];
        float4 o;
        o.x = acc[i][0] * nv; o.y = acc[i][1] * nv;
        o.z = acc[i][2] * nv; o.w = acc[i][3] * nv;
        *(float4*)(out + (size_t)row * FF + cbase + tx * 4) = o;
    }
}

// ---------- per-bin adjacency GEMM: E[r,c] = norm[r]*sum_j dm[r,j]*T[j,c] ----------
__global__ __launch_bounds__(256) void k_adj(const float* __restrict__ dm, const float* __restrict__ T,
                                             const float* __restrict__ norm, float* __restrict__ out) {
    __shared__ float Ds[128][37];
    __shared__ float Ts[32][68];
    int g = blockIdx.x, cb = blockIdx.y;
    int tid = threadIdx.x;
    int cbase = cb * 64;
    int tx = tid & 15, ty = tid >> 4;
    float acc[8][4] = {};
    for (int kb = 0; kb < 128; kb += 32) {
        __syncthreads();
        {
            int row = tid >> 1, col0 = (tid & 1) * 16;
            const float* dp = dm + (size_t)g * 16384 + (size_t)row * 128 + kb + col0;
            #pragma unroll
            for (int q = 0; q < 4; q++) {
                float4 v = *(const float4*)(dp + q * 4);
                Ds[row][col0 + q * 4 + 0] = v.x; Ds[row][col0 + q * 4 + 1] = v.y;
                Ds[row][col0 + q * 4 + 2] = v.z; Ds[row][col0 + q * 4 + 3] = v.w;
            }
        }
        {
            int kk = tid >> 3, cc0 = (tid & 7) * 8;
            const float* tp = T + (size_t)(g * 128 + kb + kk) * FF + cbase + cc0;
            float4 v0 = *(const float4*)tp;
            float4 v1 = *(const float4*)(tp + 4);
            Ts[kk][cc0 + 0] = v0.x; Ts[kk][cc0 + 1] = v0.y;
            Ts[kk][cc0 + 2] = v0.z; Ts[kk][cc0 + 3] = v0.w;
            Ts[kk][cc0 + 4] = v1.x; Ts[kk][cc0 + 5] = v1.y;
            Ts[kk][cc0 + 6] = v1.z; Ts[kk][cc0 + 7] = v1.w;
        }
        __syncthreads();
        for (int kk = 0; kk < 32; kk++) {
            float a[8], bv[4];
            #pragma unroll
            for (int i = 0; i < 8; i++) a[i] = Ds[ty * 8 + i][kk];
            #pragma unroll
            for (int jj = 0; jj < 4; jj++) bv[jj] = Ts[kk][tx * 4 + jj];
            #pragma unroll
            for (int i = 0; i < 8; i++)
                #pragma unroll
                for (int jj = 0; jj < 4; jj++) acc[i][jj] += a[i] * bv[jj];
        }
    }
    #pragma unroll
    for (int i = 0; i < 8; i++) {
        int row = g * 128 + ty * 8 + i;
        float nv = norm[row];
        float4 o;
        o.x = acc[i][0] * nv; o.y = acc[i][1] * nv;
        o.z = acc[i][2] * nv; o.w = acc[i][3] * nv;
        *(float4*)(out + (size_t)row * FF + cbase + tx * 4) = o;
    }
}

// ---------- combine: dual GEMM (wh, wt) + gate/elu epilogue ----------
__global__ __launch_bounds__(256) void k_comb(const float* __restrict__ Ain, const int* __restrict__ flat,
                                              const float* __restrict__ Wh, const float* __restrict__ Wt,
                                              const float* __restrict__ bt, const float* __restrict__ FH,
                                              const float* __restrict__ mf, float* __restrict__ out) {
    __shared__ float As[64][36];
    __shared__ float Hs[32][68];
    __shared__ float Gs[32][68];
    int rb = blockIdx.x, cb = blockIdx.y;
    int tid = threadIdx.x;
    int rowbase = rb * 64, cbase = cb * 64;
    int tx = tid & 15, ty = tid >> 4;
    float accH[4][4] = {};
    float accG[4][4] = {};
    for (int kb = 0; kb < FF; kb += 32) {
        __syncthreads();
        {
            int row = tid >> 2, col0 = (tid & 3) * 8;
            int src = flat ? flat[rowbase + row] : (rowbase + row);
            const float* ap = Ain + (size_t)src * FF + kb + col0;
            float4 v0 = *(const float4*)ap;
            float4 v1 = *(const float4*)(ap + 4);
            As[row][col0 + 0] = v0.x; As[row][col0 + 1] = v0.y;
            As[row][col0 + 2] = v0.z; As[row][col0 + 3] = v0.w;
            As[row][col0 + 4] = v1.x; As[row][col0 + 5] = v1.y;
            As[row][col0 + 6] = v1.z; As[row][col0 + 7] = v1.w;
        }
        {
            int kk = tid >> 3, cc0 = (tid & 7) * 8;
            const float* wp = Wh + (size_t)(kb + kk) * FF + cbase + cc0;
            float4 v0 = *(const float4*)wp;
            float4 v1 = *(const float4*)(wp + 4);
            Hs[kk][cc0 + 0] = v0.x; Hs[kk][cc0 + 1] = v0.y;
            Hs[kk][cc0 + 2] = v0.z; Hs[kk][cc0 + 3] = v0.w;
            Hs[kk][cc0 + 4] = v1.x; Hs[kk][cc0 + 5] = v1.y;
            Hs[kk][cc0 + 6] = v1.z; Hs[kk][cc0 + 7] = v1.w;
            const float* gp = Wt + (size_t)(kb + kk) * FF + cbase + cc0;
            float4 g0 = *(const float4*)gp;
            float4 g1 = *(const float4*)(gp + 4);
            Gs[kk][cc0 + 0] = g0.x; Gs[kk][cc0 + 1] = g0.y;
            Gs[kk][cc0 + 2] = g0.z; Gs[kk][cc0 + 3] = g0.w;
            Gs[kk][cc0 + 4] = g1.x; Gs[kk][cc0 + 5] = g1.y;
            Gs[kk][cc0 + 6] = g1.z; Gs[kk][cc0 + 7] = g1.w;
        }
        __syncthreads();
        for (int kk = 0; kk < 32; kk++) {
            float a[4], bh[4], bg[4];
            #pragma unroll
            for (int i = 0; i < 4; i++) a[i] = As[ty * 4 + i][kk];
            #pragma unroll
            for (int jj = 0; jj < 4; jj++) { bh[jj] = Hs[kk][tx * 4 + jj]; bg[jj] = Gs[kk][tx * 4 + jj]; }
            #pragma unroll
            for (int i = 0; i < 4; i++)
                #pragma unroll
                for (int jj = 0; jj < 4; jj++) {
                    accH[i][jj] += a[i] * bh[jj];
                    accG[i][jj] += a[i] * bg[jj];
                }
        }
    }
    #pragma unroll
    for (int i = 0; i < 4; i++) {
        int row = rowbase + ty * 4 + i;
        float m = mf[row];
        #pragma unroll
        for (int jj = 0; jj < 4; jj++) {
            int c = cbase + tx * 4 + jj;
            float gate = 1.f / (1.f + expf(-(accG[i][jj] + bt[c])));
            float het = m * accH[i][jj];
            float fh = FH[(size_t)row * FF + c];
            float o = gate * fh + (1.f - gate) * het;
            o = (o > 0.f) ? o : expm1f(o);
            out[(size_t)row * FF + c] = o * m;
        }
    }
}

// ---------- final scatter ----------
__global__ void k_scat(const float* __restrict__ src, const int* __restrict__ flat,
                       float* __restrict__ dst) {
    int r = blockIdx.x;
    int c = threadIdx.x;
    dst[(size_t)flat[r] * FF + c] = src[(size_t)r * FF + c];
}

extern "C" void kernel_launch(void* const* d_in, const int* in_sizes, int n_in,
                              void* d_out, int out_size, void* d_ws, size_t ws_size,
                              hipStream_t stream) {
    const float* x    = (const float*)d_in[0];
    const void*  msk  = d_in[1];
    const float* ln_g = (const float*)d_in[2];
    const float* ln_b = (const float*)d_in[3];
    const float* w1   = (const float*)d_in[4];
    const float* b1   = (const float*)d_in[5];
    const float* w2   = (const float*)d_in[6];
    const float* b2   = (const float*)d_in[7];
    const float* rot  = (const float*)d_in[8];
    const float* th0  = (const float*)d_in[9];
    const float* wh0  = (const float*)d_in[10];
    const float* wt0  = (const float*)d_in[11];
    const float* bt0  = (const float*)d_in[12];
    const float* th1  = (const float*)d_in[13];
    const float* wh1  = (const float*)d_in[14];
    const float* wt1  = (const float*)d_in[15];
    const float* bt1  = (const float*)d_in[16];

    char* ws = (char*)d_ws;
    float* R0   = (float*)(ws + OFF_R0);
    float* xd   = R0;                      // alias: xd dead before R0 reused as FH
    float* R1   = (float*)(ws + OFF_R1);
    float* dm   = (float*)(ws + OFF_DM);
    float* norm = (float*)(ws + OFF_NORM);
    float* mf   = (float*)(ws + OFF_MF);
    int*   bin  = (int*)(ws + OFF_BIN);
    int*   flat = (int*)(ws + OFF_FLAT);
    int*   mski = (int*)(ws + OFF_MSKI);
    int*   hist = (int*)(ws + OFF_HIST);
    int*   offs = (int*)(ws + OFF_OFFS);
    int*   flag = (int*)(ws + OFF_FLAG);
    float* xn   = (float*)d_out;           // d_out: xn, then FH2, then final output

    hipMemsetAsync(hist, 0, HISTBYTES, stream);
    k_maskflag<<<1, 256, 0, stream>>>((const int*)msk, flag);
    k_masknorm<<<PTS / 256, 256, 0, stream>>>(msk, flag, mski);
    k_stage1<<<PTS / 16, 256, 0, stream>>>(x, ln_g, ln_b, w1, b1, w2, b2, rot, mski, xn, xd, bin);
    k_count<<<800, 128, 0, stream>>>(bin, hist);
    k_offsets<<<8, 256, 0, stream>>>(hist, offs);
    k_scatter<<<800, 128, 0, stream>>>(bin, offs, mski, flat, mf);
    k_dm<<<800, 256, 0, stream>>>(xd, flat, mf, dm);
    k_normk<<<800, 128, 0, stream>>>(dm, mf, norm);
    // layer 0
    k_proj<<<dim3(1600, 4), 256, 0, stream>>>(xn, flat, th0, norm, R1);       // T -> R1
    k_adj<<<dim3(800, 4), 256, 0, stream>>>(dm, R1, norm, R0);                // FH -> R0
    k_comb<<<dim3(1600, 4), 256, 0, stream>>>(xn, flat, wh0, wt0, bt0, R0, mf, R1);  // out0 -> R1
    // layer 1
    k_proj<<<dim3(1600, 4), 256, 0, stream>>>(R1, nullptr, th1, norm, R0);    // T2 -> R0
    k_adj<<<dim3(800, 4), 256, 0, stream>>>(dm, R0, norm, xn);                // FH2 -> d_out
    k_comb<<<dim3(1600, 4), 256, 0, stream>>>(R1, nullptr, wh1, wt1, bt1, xn, mf, R0); // out1 -> R0
    k_scat<<<PTS, 256, 0, stream>>>(R0, flat, (float*)d_out);
}

// Round 2
// 1181.136 us; speedup vs baseline: 2.3930x; 2.3930x over previous
//
#include <hip/hip_runtime.h>
#include <math.h>

#define BB 8
#define NN 12800
#define FF 256
#define DDIM 128
#define NBINS 100
#define BSIZE 128
#define NROT 50
#define NIDS 199
#define PTS (BB*NN)            // 102400
#define PITCH_T ((size_t)102400)

// ---- workspace layout (bytes) ----
#define OFF_FHT  ((size_t)0)            // 104857600 : FH transposed fp32 [256][102400]
#define OFF_TT   ((size_t)104857600)    // 52428800  : T transposed bf16 [256][102400]
#define OFF_OUT0 ((size_t)157286400)    // 52428800  : out0 bf16 [102400][256]
#define OFF_DMB  ((size_t)209715200)    // 26214400  : dm bf16 [800][128][128]
#define OFF_WB   ((size_t)235929600)    // 786432    : 6 weights bf16 transposed [256][256]
#define OFF_NORM ((size_t)236716032)    // 409600
#define OFF_MF   ((size_t)237125632)    // 409600
#define OFF_BIN  ((size_t)237535232)    // 409600 (int)
#define OFF_FLAT ((size_t)237944832)    // 409600 (int)
#define OFF_MSKI ((size_t)238354432)    // 409600 (int)
#define OFF_HIST ((size_t)238764032)    // 636800 (int)
#define OFF_OFFS ((size_t)239400832)    // 636800 (int)
#define OFF_FLAG ((size_t)240037632)    // 64
#define HISTBYTES (8*100*199*4)

using short8  = __attribute__((ext_vector_type(8))) short;
using floatx4 = __attribute__((ext_vector_type(4))) float;

__device__ __forceinline__ ushort f2b(float f) {
    unsigned u = __float_as_uint(f);
    unsigned r = (u + 0x7FFFu + ((u >> 16) & 1u)) >> 16;
    return (ushort)r;
}

// ---------- mask dtype sniffing ----------
__global__ void k_maskflag(const int* mi, int* flag) {
    __shared__ int notInt, notFloat;
    if (threadIdx.x == 0) { notInt = 0; notFloat = 0; }
    __syncthreads();
    int v = mi[threadIdx.x];
    if (v != 0 && v != 1) atomicOr(&notInt, 1);
    if (v != 0 && v != 0x3F800000) atomicOr(&notFloat, 1);
    __syncthreads();
    if (threadIdx.x == 0) flag[0] = (!notInt) ? 0 : ((!notFloat) ? 2 : 1);
}

__global__ void k_masknorm(const void* msk, const int* flag, int* mski) {
    int i = blockIdx.x * blockDim.x + threadIdx.x;
    if (i >= PTS) return;
    int f = flag[0];
    int v;
    if (f == 0)      v = ((const int*)msk)[i] != 0;
    else if (f == 2) v = ((const float*)msk)[i] != 0.0f;
    else             v = ((const unsigned char*)msk)[i] != 0;
    mski[i] = v;
}

// ---------- weight prep: fp32 [k][n] -> bf16 transposed [n][k] ----------
__global__ __launch_bounds__(256) void k_wprep(
    const float* s0, const float* s1, const float* s2,
    const float* s3, const float* s4, const float* s5,
    ushort* d0, ushort* d1, ushort* d2, ushort* d3, ushort* d4, ushort* d5)
{
    __shared__ float Ls[64 * 65];
    const float* src; ushort* dst;
    switch (blockIdx.y) {
        case 0: src = s0; dst = d0; break;
        case 1: src = s1; dst = d1; break;
        case 2: src = s2; dst = d2; break;
        case 3: src = s3; dst = d3; break;
        case 4: src = s4; dst = d4; break;
        default: src = s5; dst = d5; break;
    }
    int t = blockIdx.x;
    int kb = (t & 3) * 64, nb = (t >> 2) * 64;
    int tid = threadIdx.x;
    for (int q = 0; q < 4; ++q) {
        int g = q * 256 + tid;
        int kl = g >> 4, f4 = g & 15;
        float4 v = *(const float4*)(src + (size_t)(kb + kl) * 256 + nb + f4 * 4);
        Ls[kl * 65 + f4 * 4 + 0] = v.x;
        Ls[kl * 65 + f4 * 4 + 1] = v.y;
        Ls[kl * 65 + f4 * 4 + 2] = v.z;
        Ls[kl * 65 + f4 * 4 + 3] = v.w;
    }
    __syncthreads();
    for (int q = 0; q < 2; ++q) {
        int g = q * 256 + tid;
        int nl = g >> 3, wg = g & 7;
        ushort o[8];
        #pragma unroll
        for (int c = 0; c < 8; ++c) o[c] = f2b(Ls[(wg * 8 + c) * 65 + nl]);
        uint4 ou;
        ou.x = (unsigned)o[0] | ((unsigned)o[1] << 16);
        ou.y = (unsigned)o[2] | ((unsigned)o[3] << 16);
        ou.z = (unsigned)o[4] | ((unsigned)o[5] << 16);
        ou.w = (unsigned)o[6] | ((unsigned)o[7] << 16);
        *(uint4*)(dst + (size_t)(nb + nl) * 256 + kb + wg * 8) = ou;
    }
}

// ---------- stage 1: LN + FFN + rot + argmax (fp64 chain) ----------
__global__ __launch_bounds__(256) void k_stage1(
    const float* __restrict__ x, const float* __restrict__ g, const float* __restrict__ be,
    const float* __restrict__ w1, const float* __restrict__ b1,
    const float* __restrict__ w2, const float* __restrict__ b2,
    const float* __restrict__ rot, const int* __restrict__ mski,
    ushort* __restrict__ xn_out, float* __restrict__ xd_out, int* __restrict__ bin_out)
{
    __shared__ double xs[16][FF];
    __shared__ double hs[16][DDIM];
    int tid = threadIdx.x;
    int base = blockIdx.x * 16;

    {   // phase 0: load + layernorm
        int pl = tid >> 4, t = tid & 15;
        int pt = base + pl;
        const float* xr = x + (size_t)pt * FF;
        double s = 0.0;
        for (int i = t; i < FF; i += 16) { double v = (double)xr[i]; xs[pl][i] = v; s += v; }
        for (int off = 1; off < 16; off <<= 1) s += __shfl_xor(s, off, 16);
        double mu = s * (1.0 / 256.0);
        double s2 = 0.0;
        for (int i = t; i < FF; i += 16) { double d = xs[pl][i] - mu; s2 += d * d; }
        for (int off = 1; off < 16; off <<= 1) s2 += __shfl_xor(s2, off, 16);
        double rs = 1.0 / sqrt(s2 * (1.0 / 256.0) + 1e-6);
        ushort* xo = xn_out + (size_t)pt * FF;
        for (int i = t; i < FF; i += 16) {
            double v = (xs[pl][i] - mu) * rs * (double)g[i] + (double)be[i];
            xs[pl][i] = v;
            xo[i] = f2b((float)v);
        }
    }
    __syncthreads();
    {   // phase 1: h = elu(xn @ w1 + b1)
        int j = tid & 127, pg = tid >> 7;
        double acc[8];
        double bj = (double)b1[j];
        #pragma unroll
        for (int r = 0; r < 8; r++) acc[r] = bj;
        for (int k = 0; k < FF; k++) {
            double w = (double)w1[k * DDIM + j];
            #pragma unroll
            for (int r = 0; r < 8; r++) acc[r] += xs[pg * 8 + r][k] * w;
        }
        #pragma unroll
        for (int r = 0; r < 8; r++) {
            double h = acc[r];
            hs[pg * 8 + r][j] = (h > 0.0) ? h : expm1(h);
        }
    }
    __syncthreads();
    {   // phase 2: xd = h @ w2 + b2
        int j = tid & 127, pg = tid >> 7;
        double acc[8];
        double bj = (double)b2[j];
        #pragma unroll
        for (int r = 0; r < 8; r++) acc[r] = bj;
        for (int k = 0; k < DDIM; k++) {
            double w = (double)w2[k * DDIM + j];
            #pragma unroll
            for (int r = 0; r < 8; r++) acc[r] += hs[pg * 8 + r][k] * w;
        }
        __syncthreads();
        #pragma unroll
        for (int r = 0; r < 8; r++) {
            int p = pg * 8 + r;
            xs[p][j] = acc[r];
            xd_out[(size_t)(base + p) * DDIM + j] = (float)acc[r];
        }
    }
    __syncthreads();
    {   // phase 3: mul = xd @ rot[:, :50]; argmax over [mul, -mul]
        int c = tid & 63, wv = tid >> 6;
        for (int r = 0; r < 4; r++) {
            int p = wv * 4 + r;
            double v; int idx;
            if (c < NROT) {
                double m = 0.0;
                for (int k = 0; k < DDIM; k++) m += xs[p][k] * (double)rot[k * 100 + c];
                if (m >= 0.0) { v = m; idx = c; } else { v = -m; idx = 50 + c; }
            } else { v = -1e300; idx = 1 << 29; }
            #pragma unroll
            for (int off = 1; off < 64; off <<= 1) {
                double ov = __shfl_xor(v, off, 64);
                int oi = __shfl_xor(idx, off, 64);
                if (ov > v || (ov == v && oi < idx)) { v = ov; idx = oi; }
            }
            if (c == 0) {
                int pt = base + p;
                bin_out[pt] = idx + (mski[pt] ? 0 : (NBINS - 1));
            }
        }
    }
}

// ---------- binning: stable counting sort ----------
__global__ void k_count(const int* __restrict__ bin, int* __restrict__ hist) {
    int c = blockIdx.x % 100, b = blockIdx.x / 100;
    int t = threadIdx.x;
    int v = bin[b * NN + c * BSIZE + t];
    atomicAdd(&hist[(b * 100 + c) * NIDS + v], 1);
}

__global__ void k_offsets(const int* __restrict__ hist, int* __restrict__ offs) {
    __shared__ int tot[NIDS];
    __shared__ int start[NIDS];
    int b = blockIdx.x, v = threadIdx.x;
    if (v < NIDS) {
        int s = 0;
        for (int c = 0; c < 100; c++) s += hist[(b * 100 + c) * NIDS + v];
        tot[v] = s;
    }
    __syncthreads();
    if (threadIdx.x == 0) {
        int run = 0;
        for (int i = 0; i < NIDS; i++) { start[i] = run; run += tot[i]; }
    }
    __syncthreads();
    if (v < NIDS) {
        int run = start[v];
        for (int c = 0; c < 100; c++) {
            offs[(b * 100 + c) * NIDS + v] = run;
            run += hist[(b * 100 + c) * NIDS + v];
        }
    }
}

__global__ void k_scatter(const int* __restrict__ bin, const int* __restrict__ offs,
                          const int* __restrict__ mski, int* __restrict__ flat,
                          float* __restrict__ mf) {
    __shared__ int sv[BSIZE];
    int c = blockIdx.x % 100, b = blockIdx.x / 100;
    int t = threadIdx.x;
    int n = c * BSIZE + t;
    int v = bin[b * NN + n];
    sv[t] = v;
    __syncthreads();
    int rank = 0;
    for (int u = 0; u < t; u++) rank += (sv[u] == v);
    int r = offs[(b * 100 + c) * NIDS + v] + rank;
    flat[b * NN + r] = b * NN + n;
    mf[b * NN + r] = mski[b * NN + n] ? 1.0f : 0.0f;
}

// ---------- per-bin pairwise kernel matrix (fp32 tiled), fused deg/norm ----------
__global__ __launch_bounds__(256) void k_dm(const float* __restrict__ xd, const int* __restrict__ flat,
                                            const float* __restrict__ mf, ushort* __restrict__ dmb,
                                            float* __restrict__ norm) {
    __shared__ float Xs[128 * 64];
    __shared__ float na[128];
    __shared__ float ml[128];
    __shared__ float ps[128 * 16];
    int g = blockIdx.x, tid = threadIdx.x;
    int tx = tid & 15, ty = tid >> 4;
    int rowbase = g * 128;
    if (tid < 128) ml[tid] = mf[rowbase + tid];
    float acc[8][8];
    #pragma unroll
    for (int i = 0; i < 8; i++)
        #pragma unroll
        for (int j = 0; j < 8; j++) acc[i][j] = 0.f;
    float nap[8];
    #pragma unroll
    for (int j = 0; j < 8; j++) nap[j] = 0.f;

    for (int kh = 0; kh < 2; ++kh) {
        __syncthreads();
        for (int q = 0; q < 8; ++q) {
            int gg = q * 256 + tid;
            int row = gg >> 4, f4 = gg & 15;
            int srow = flat[rowbase + row];
            float4 v = *(const float4*)(xd + (size_t)srow * DDIM + kh * 64 + f4 * 4);
            int f4s = f4 ^ ((row >> 3) & 7);
            *(float4*)(Xs + row * 64 + f4s * 4) = v;
        }
        __syncthreads();
        for (int k4 = 0; k4 < 16; ++k4) {
            int sa = (k4 ^ (ty & 7)) << 2;
            int sb = (k4 ^ (tx & 7)) << 2;
            float4 av[8], bv[8];
            #pragma unroll
            for (int i = 0; i < 8; i++) av[i] = *(const float4*)(Xs + (ty * 8 + i) * 64 + sa);
            #pragma unroll
            for (int j = 0; j < 8; j++) bv[j] = *(const float4*)(Xs + (tx * 8 + j) * 64 + sb);
            if (ty == 0) {
                #pragma unroll
                for (int j = 0; j < 8; j++)
                    nap[j] += bv[j].x * bv[j].x + bv[j].y * bv[j].y + bv[j].z * bv[j].z + bv[j].w * bv[j].w;
            }
            #pragma unroll
            for (int i = 0; i < 8; i++)
                #pragma unroll
                for (int j = 0; j < 8; j++)
                    acc[i][j] += av[i].x * bv[j].x + av[i].y * bv[j].y + av[i].z * bv[j].z + av[i].w * bv[j].w;
        }
    }
    if (ty == 0) {
        #pragma unroll
        for (int j = 0; j < 8; j++) na[tx * 8 + j] = nap[j];
    }
    __syncthreads();
    #pragma unroll
    for (int i = 0; i < 8; ++i) {
        int r = ty * 8 + i;
        float nai = na[r], mi = ml[r];
        float rs = 0.f;
        ushort o[8];
        #pragma unroll
        for (int j = 0; j < 8; ++j) {
            int c = tx * 8 + j;
            float D2 = nai - 2.f * acc[i][j] + na[c];
            float dv = expf(-0.1f * sqrtf(fmaxf(D2, 1e-6f)));
            dv *= mi * ml[c];
            rs += dv;
            o[j] = f2b(dv);
        }
        uint4 ou;
        ou.x = (unsigned)o[0] | ((unsigned)o[1] << 16);
        ou.y = (unsigned)o[2] | ((unsigned)o[3] << 16);
        ou.z = (unsigned)o[4] | ((unsigned)o[5] << 16);
        ou.w = (unsigned)o[6] | ((unsigned)o[7] << 16);
        *(uint4*)(dmb + (size_t)g * 16384 + r * 128 + tx * 8) = ou;
        ps[r * 16 + tx] = rs;
    }
    __syncthreads();
    if (tid < 128) {
        float deg = 0.f;
        for (int t2 = 0; t2 < 16; ++t2) deg += ps[tid * 16 + t2];
        deg = fminf(deg, 1000.0f);
        float nv = 1.0f / sqrtf(deg + 1e-6f);
        norm[rowbase + tid] = nv * ml[tid];
    }
}

// ---------- MFMA helpers ----------
// LDS tile: [rows][64 k] bf16, row pitch 128B, 4-word-group XOR swizzle
__device__ __forceinline__ void stage_bf16(const ushort* __restrict__ src, size_t pitch,
                                           const int* __restrict__ rowmap, int rowbase, size_t kbase,
                                           ushort* lds, int nrows, int tid, int nthr) {
    int total = nrows * 8;
    for (int g = tid; g < total; g += nthr) {
        int row = g >> 3, wg = g & 7;
        size_t srow = rowmap ? (size_t)rowmap[rowbase + row] : (size_t)(rowbase + row);
        uint4 v = *(const uint4*)(src + srow * pitch + kbase + wg * 8);
        int w0 = (wg * 4) ^ ((row & 7) << 2);
        *(uint4*)((char*)lds + row * 128 + w0 * 4) = v;
    }
}

__device__ __forceinline__ short8 frag_ld(const ushort* lds, int row, int kc, int lane) {
    int w0 = (kc * 16 + ((lane >> 4) << 2)) ^ ((row & 7) << 2);
    return *(const short8*)((const char*)lds + row * 128 + w0 * 4);
}

// ---------- T = (A @ W) * norm, stored transposed bf16 [c][row] ----------
__global__ __launch_bounds__(256) void k_proj(const ushort* __restrict__ A, const int* __restrict__ rowmap,
                                              const ushort* __restrict__ Wt, const float* __restrict__ norm,
                                              ushort* __restrict__ Tt) {
    __shared__ ushort lA[128 * 64];
    __shared__ ushort lB[128 * 64];
    int tid = threadIdx.x, lane = tid & 63, wid = tid >> 6;
    int rowbase = blockIdx.x * 128, nbase = blockIdx.y * 128;
    int wm = (wid >> 1) * 64, wn = (wid & 1) * 64;
    int l15 = lane & 15;
    floatx4 zf = {0.f, 0.f, 0.f, 0.f};
    floatx4 acc[4][4];
    #pragma unroll
    for (int m = 0; m < 4; m++)
        #pragma unroll
        for (int n = 0; n < 4; n++) acc[m][n] = zf;
    for (int kb = 0; kb < 4; ++kb) {
        __syncthreads();
        stage_bf16(A, 256, rowmap, rowbase, (size_t)kb * 64, lA, 128, tid, 256);
        stage_bf16(Wt, 256, nullptr, nbase, (size_t)kb * 64, lB, 128, tid, 256);
        __syncthreads();
        #pragma unroll
        for (int kc = 0; kc < 2; ++kc) {
            short8 a[4], b[4];
            #pragma unroll
            for (int m = 0; m < 4; m++) a[m] = frag_ld(lA, wm + m * 16 + l15, kc, lane);
            #pragma unroll
            for (int n = 0; n < 4; n++) b[n] = frag_ld(lB, wn + n * 16 + l15, kc, lane);
            #pragma unroll
            for (int m = 0; m < 4; m++)
                #pragma unroll
                for (int n = 0; n < 4; n++)
                    acc[m][n] = __builtin_amdgcn_mfma_f32_16x16x32_bf16(a[m], b[n], acc[m][n], 0, 0, 0);
        }
    }
    int r4 = (lane >> 4) * 4;
    #pragma unroll
    for (int m = 0; m < 4; m++) {
        int r0 = rowbase + wm + m * 16 + r4;
        float4 nv = *(const float4*)(norm + r0);
        #pragma unroll
        for (int n = 0; n < 4; n++) {
            int cg = nbase + wn + n * 16 + l15;
            ushort4 o;
            o.x = f2b(acc[m][n][0] * nv.x);
            o.y = f2b(acc[m][n][1] * nv.y);
            o.z = f2b(acc[m][n][2] * nv.z);
            o.w = f2b(acc[m][n][3] * nv.w);
            *(ushort4*)(Tt + (size_t)cg * PITCH_T + r0) = o;
        }
    }
}

// ---------- FH = (dm @ T) * norm, stored transposed fp32 [c][row] ----------
__global__ __launch_bounds__(512) void k_adj(const ushort* __restrict__ dmb, const ushort* __restrict__ Tt,
                                             const float* __restrict__ norm, float* __restrict__ FHt) {
    __shared__ ushort lA[128 * 64];
    __shared__ ushort lB[256 * 64];
    int g = blockIdx.x;
    int tid = threadIdx.x, lane = tid & 63, wid = tid >> 6;
    int wm = (wid >> 2) * 64, wn = (wid & 3) * 64;
    int l15 = lane & 15;
    const ushort* dmg = dmb + (size_t)g * 16384;
    floatx4 zf = {0.f, 0.f, 0.f, 0.f};
    floatx4 acc[4][4];
    #pragma unroll
    for (int m = 0; m < 4; m++)
        #pragma unroll
        for (int n = 0; n < 4; n++) acc[m][n] = zf;
    for (int kb = 0; kb < 2; ++kb) {
        __syncthreads();
        stage_bf16(dmg, 128, nullptr, 0, (size_t)kb * 64, lA, 128, tid, 512);
        stage_bf16(Tt, PITCH_T, nullptr, 0, (size_t)g * 128 + kb * 64, lB, 256, tid, 512);
        __syncthreads();
        #pragma unroll
        for (int kc = 0; kc < 2; ++kc) {
            short8 a[4], b[4];
            #pragma unroll
            for (int m = 0; m < 4; m++) a[m] = frag_ld(lA, wm + m * 16 + l15, kc, lane);
            #pragma unroll
            for (int n = 0; n < 4; n++) b[n] = frag_ld(lB, wn + n * 16 + l15, kc, lane);
            #pragma unroll
            for (int m = 0; m < 4; m++)
                #pragma unroll
                for (int n = 0; n < 4; n++)
                    acc[m][n] = __builtin_amdgcn_mfma_f32_16x16x32_bf16(a[m], b[n], acc[m][n], 0, 0, 0);
        }
    }
    int r4 = (lane >> 4) * 4;
    #pragma unroll
    for (int m = 0; m < 4; m++) {
        int r0l = wm + m * 16 + r4;
        float4 nv = *(const float4*)(norm + g * 128 + r0l);
        #pragma unroll
        for (int n = 0; n < 4; n++) {
            int cg = wn + n * 16 + l15;
            float4 o;
            o.x = acc[m][n][0] * nv.x;
            o.y = acc[m][n][1] * nv.y;
            o.z = acc[m][n][2] * nv.z;
            o.w = acc[m][n][3] * nv.w;
            *(float4*)(FHt + (size_t)cg * PITCH_T + g * 128 + r0l) = o;
        }
    }
}

// ---------- combine: dual GEMM (wh, wt) + gate/elu epilogue ----------
template<int LAYER>
__global__ __launch_bounds__(512) void k_comb(const ushort* __restrict__ A, const int* __restrict__ rowmap,
                                              const ushort* __restrict__ WhT, const ushort* __restrict__ WtT,
                                              const float* __restrict__ bt, const float* __restrict__ FHt,
                                              const float* __restrict__ mf,
                                              ushort* __restrict__ outb, float* __restrict__ outf,
                                              const int* __restrict__ flatscat) {
    __shared__ ushort lA[128 * 64];
    __shared__ ushort lH[128 * 64];
    __shared__ ushort lG[128 * 64];
    int tid = threadIdx.x, lane = tid & 63, wid = tid >> 6;
    int rowbase = blockIdx.x * 128, nbase = blockIdx.y * 128;
    int wm = (wid >> 2) * 64, wn = (wid & 3) * 32;
    int l15 = lane & 15;
    floatx4 zf = {0.f, 0.f, 0.f, 0.f};
    floatx4 accH[4][2], accG[4][2];
    #pragma unroll
    for (int m = 0; m < 4; m++)
        #pragma unroll
        for (int n = 0; n < 2; n++) { accH[m][n] = zf; accG[m][n] = zf; }
    for (int kb = 0; kb < 4; ++kb) {
        __syncthreads();
        stage_bf16(A, 256, rowmap, rowbase, (size_t)kb * 64, lA, 128, tid, 512);
        stage_bf16(WhT, 256, nullptr, nbase, (size_t)kb * 64, lH, 128, tid, 512);
        stage_bf16(WtT, 256, nullptr, nbase, (size_t)kb * 64, lG, 128, tid, 512);
        __syncthreads();
        #pragma unroll
        for (int kc = 0; kc < 2; ++kc) {
            short8 a[4], bh[2], bg[2];
            #pragma unroll
            for (int m = 0; m < 4; m++) a[m] = frag_ld(lA, wm + m * 16 + l15, kc, lane);
            #pragma unroll
            for (int n = 0; n < 2; n++) {
                bh[n] = frag_ld(lH, wn + n * 16 + l15, kc, lane);
                bg[n] = frag_ld(lG, wn + n * 16 + l15, kc, lane);
            }
            #pragma unroll
            for (int m = 0; m < 4; m++)
                #pragma unroll
                for (int n = 0; n < 2; n++) {
                    accH[m][n] = __builtin_amdgcn_mfma_f32_16x16x32_bf16(a[m], bh[n], accH[m][n], 0, 0, 0);
                    accG[m][n] = __builtin_amdgcn_mfma_f32_16x16x32_bf16(a[m], bg[n], accG[m][n], 0, 0, 0);
                }
        }
    }
    int r4 = (lane >> 4) * 4;
    int base = wid * 512;
    for (int m = 0; m < 4; m++) {
        int r0l = wm + m * 16 + r4;
        int r0g = rowbase + r0l;
        float4 mv = *(const float4*)(mf + r0g);
        float mvv[4] = {mv.x, mv.y, mv.z, mv.w};
        float vals[2][4];
        #pragma unroll
        for (int n = 0; n < 2; n++) {
            int cg = nbase + wn + n * 16 + l15;
            float btc = bt[cg];
            float4 fh = *(const float4*)(FHt + (size_t)cg * PITCH_T + r0g);
            float fhv[4] = {fh.x, fh.y, fh.z, fh.w};
            #pragma unroll
            for (int i = 0; i < 4; i++) {
                float gate = 1.f / (1.f + expf(-(accG[m][n][i] + btc)));
                float het = mvv[i] * accH[m][n][i];
                float o = gate * fhv[i] + (1.f - gate) * het;
                o = (o > 0.f) ? o : expm1f(o);
                vals[n][i] = o * mvv[i];
            }
        }
        __syncthreads();
        if (LAYER == 0) {
            ushort* Ls = lA;
            #pragma unroll
            for (int n = 0; n < 2; n++)
                #pragma unroll
                for (int i = 0; i < 4; i++)
                    Ls[base + (r4 + i) * 32 + n * 16 + l15] = f2b(vals[n][i]);
            __syncthreads();
            #pragma unroll
            for (int it = 0; it < 2; ++it) {
                int lr = (lane >> 3) + it * 8;
                int lc4 = (lane & 7) * 4;
                ushort4 tv = *(const ushort4*)(Ls + base + lr * 32 + lc4);
                int rg = rowbase + wm + m * 16 + lr;
                *(ushort4*)(outb + (size_t)rg * 256 + nbase + wn + lc4) = tv;
            }
        } else {
            float* Ls = (float*)lA;
            #pragma unroll
            for (int n = 0; n < 2; n++)
                #pragma unroll
                for (int i = 0; i < 4; i++)
                    Ls[base + (r4 + i) * 32 + n * 16 + l15] = vals[n][i];
            __syncthreads();
            #pragma unroll
            for (int it = 0; it < 2; ++it) {
                int lr = (lane >> 3) + it * 8;
                int lc4 = (lane & 7) * 4;
                float4 tv = *(const float4*)(Ls + base + lr * 32 + lc4);
                int rg = rowbase + wm + m * 16 + lr;
                int dst = flatscat[rg];
                *(float4*)(outf + (size_t)dst * 256 + nbase + wn + lc4) = tv;
            }
        }
    }
}

extern "C" void kernel_launch(void* const* d_in, const int* in_sizes, int n_in,
                              void* d_out, int out_size, void* d_ws, size_t ws_size,
                              hipStream_t stream) {
    const float* x    = (const float*)d_in[0];
    const void*  msk  = d_in[1];
    const float* ln_g = (const float*)d_in[2];
    const float* ln_b = (const float*)d_in[3];
    const float* w1   = (const float*)d_in[4];
    const float* b1   = (const float*)d_in[5];
    const float* w2   = (const float*)d_in[6];
    const float* b2   = (const float*)d_in[7];
    const float* rot  = (const float*)d_in[8];
    const float* th0  = (const float*)d_in[9];
    const float* wh0  = (const float*)d_in[10];
    const float* wt0  = (const float*)d_in[11];
    const float* bt0  = (const float*)d_in[12];
    const float* th1  = (const float*)d_in[13];
    const float* wh1  = (const float*)d_in[14];
    const float* wt1  = (const float*)d_in[15];
    const float* bt1  = (const float*)d_in[16];

    char* ws = (char*)d_ws;
    float*  FHt  = (float*)(ws + OFF_FHT);
    ushort* Tt   = (ushort*)(ws + OFF_TT);
    ushort* out0 = (ushort*)(ws + OFF_OUT0);
    ushort* dmb  = (ushort*)(ws + OFF_DMB);
    ushort* wb   = (ushort*)(ws + OFF_WB);
    ushort* wbth0 = wb + 0 * 65536;
    ushort* wbwh0 = wb + 1 * 65536;
    ushort* wbwt0 = wb + 2 * 65536;
    ushort* wbth1 = wb + 3 * 65536;
    ushort* wbwh1 = wb + 4 * 65536;
    ushort* wbwt1 = wb + 5 * 65536;
    float* norm = (float*)(ws + OFF_NORM);
    float* mf   = (float*)(ws + OFF_MF);
    int*   bin  = (int*)(ws + OFF_BIN);
    int*   flat = (int*)(ws + OFF_FLAT);
    int*   mski = (int*)(ws + OFF_MSKI);
    int*   hist = (int*)(ws + OFF_HIST);
    int*   offs = (int*)(ws + OFF_OFFS);
    int*   flag = (int*)(ws + OFF_FLAG);
    // d_out doubles as scratch: xd (fp32, first 52.4MB) + xn_bf16 (next 52.4MB);
    // both dead before the final fused scatter overwrites d_out.
    float*  xd  = (float*)d_out;
    ushort* xnb = (ushort*)((char*)d_out + (size_t)PTS * DDIM * 4);

    hipMemsetAsync(hist, 0, HISTBYTES, stream);
    k_maskflag<<<1, 256, 0, stream>>>((const int*)msk, flag);
    k_masknorm<<<PTS / 256, 256, 0, stream>>>(msk, flag, mski);
    k_wprep<<<dim3(16, 6), 256, 0, stream>>>(th0, wh0, wt0, th1, wh1, wt1,
                                             wbth0, wbwh0, wbwt0, wbth1, wbwh1, wbwt1);
    k_stage1<<<PTS / 16, 256, 0, stream>>>(x, ln_g, ln_b, w1, b1, w2, b2, rot, mski, xnb, xd, bin);
    k_count<<<800, 128, 0, stream>>>(bin, hist);
    k_offsets<<<8, 256, 0, stream>>>(hist, offs);
    k_scatter<<<800, 128, 0, stream>>>(bin, offs, mski, flat, mf);
    k_dm<<<800, 256, 0, stream>>>(xd, flat, mf, dmb, norm);
    // layer 0
    k_proj<<<dim3(800, 2), 256, 0, stream>>>(xnb, flat, wbth0, norm, Tt);
    k_adj<<<800, 512, 0, stream>>>(dmb, Tt, norm, FHt);
    k_comb<0><<<dim3(800, 2), 512, 0, stream>>>(xnb, flat, wbwh0, wbwt0, bt0, FHt, mf, out0, nullptr, nullptr);
    // layer 1
    k_proj<<<dim3(800, 2), 256, 0, stream>>>(out0, nullptr, wbth1, norm, Tt);
    k_adj<<<800, 512, 0, stream>>>(dmb, Tt, norm, FHt);
    k_comb<1><<<dim3(800, 2), 512, 0, stream>>>(out0, nullptr, wbwh1, wbwt1, bt1, FHt, mf, nullptr, (float*)d_out, flat);
}

// Round 3
// 1025.794 us; speedup vs baseline: 2.7554x; 1.1514x over previous
//
#include <hip/hip_runtime.h>
#include <math.h>

#define BB 8
#define NN 12800
#define FF 256
#define DDIM 128
#define NBINS 100
#define BSIZE 128
#define NROT 50
#define NIDS 199
#define PTS (BB*NN)            // 102400
#define PITCH_T ((size_t)102400)

// ---- workspace layout (bytes) ----
#define OFF_FHT  ((size_t)0)            // 104857600 : FH transposed fp32 [256][102400]
#define OFF_TT   ((size_t)104857600)    // 52428800  : T transposed bf16 [256][102400]
#define OFF_OUT0 ((size_t)157286400)    // 52428800  : out0 bf16 [102400][256]
#define OFF_DMB  ((size_t)209715200)    // 26214400  : dm bf16 [800][128][128]
#define OFF_WB   ((size_t)235929600)    // 786432    : 6 weights bf16 transposed [256][256]
#define OFF_NORM ((size_t)236716032)    // 409600
#define OFF_MF   ((size_t)237125632)    // 409600
#define OFF_BIN  ((size_t)237535232)    // 409600 (int)
#define OFF_FLAT ((size_t)237944832)    // 409600 (int)
#define OFF_MSKI ((size_t)238354432)    // 409600 (int)
#define OFF_HIST ((size_t)238764032)    // 636800 (int)
#define OFF_OFFS ((size_t)239400832)    // 636800 (int)
#define OFF_FLAG ((size_t)240037632)    // 64
#define OFF_CNT  ((size_t)240037696)    // 64
#define OFF_LIST ((size_t)240037760)    // 409600 (int)
#define HISTBYTES (8*100*199*4)

using short8  = __attribute__((ext_vector_type(8))) short;
using floatx4 = __attribute__((ext_vector_type(4))) float;

__device__ __forceinline__ ushort f2b(float f) {
    unsigned u = __float_as_uint(f);
    unsigned r = (u + 0x7FFFu + ((u >> 16) & 1u)) >> 16;
    return (ushort)r;
}

// ---------- mask dtype sniffing ----------
__global__ void k_maskflag(const int* mi, int* flag) {
    __shared__ int notInt, notFloat;
    if (threadIdx.x == 0) { notInt = 0; notFloat = 0; }
    __syncthreads();
    int v = mi[threadIdx.x];
    if (v != 0 && v != 1) atomicOr(&notInt, 1);
    if (v != 0 && v != 0x3F800000) atomicOr(&notFloat, 1);
    __syncthreads();
    if (threadIdx.x == 0) flag[0] = (!notInt) ? 0 : ((!notFloat) ? 2 : 1);
}

__global__ void k_masknorm(const void* msk, const int* flag, int* mski) {
    int i = blockIdx.x * blockDim.x + threadIdx.x;
    if (i >= PTS) return;
    int f = flag[0];
    int v;
    if (f == 0)      v = ((const int*)msk)[i] != 0;
    else if (f == 2) v = ((const float*)msk)[i] != 0.0f;
    else             v = ((const unsigned char*)msk)[i] != 0;
    mski[i] = v;
}

// ---------- weight prep: fp32 [k][n] -> bf16 transposed [n][k] ----------
__global__ __launch_bounds__(256) void k_wprep(
    const float* s0, const float* s1, const float* s2,
    const float* s3, const float* s4, const float* s5,
    ushort* d0, ushort* d1, ushort* d2, ushort* d3, ushort* d4, ushort* d5)
{
    __shared__ float Ls[64 * 65];
    const float* src; ushort* dst;
    switch (blockIdx.y) {
        case 0: src = s0; dst = d0; break;
        case 1: src = s1; dst = d1; break;
        case 2: src = s2; dst = d2; break;
        case 3: src = s3; dst = d3; break;
        case 4: src = s4; dst = d4; break;
        default: src = s5; dst = d5; break;
    }
    int t = blockIdx.x;
    int kb = (t & 3) * 64, nb = (t >> 2) * 64;
    int tid = threadIdx.x;
    for (int q = 0; q < 4; ++q) {
        int g = q * 256 + tid;
        int kl = g >> 4, f4 = g & 15;
        float4 v = *(const float4*)(src + (size_t)(kb + kl) * 256 + nb + f4 * 4);
        Ls[kl * 65 + f4 * 4 + 0] = v.x;
        Ls[kl * 65 + f4 * 4 + 1] = v.y;
        Ls[kl * 65 + f4 * 4 + 2] = v.z;
        Ls[kl * 65 + f4 * 4 + 3] = v.w;
    }
    __syncthreads();
    for (int q = 0; q < 2; ++q) {
        int g = q * 256 + tid;
        int nl = g >> 3, wg = g & 7;
        ushort o[8];
        #pragma unroll
        for (int c = 0; c < 8; ++c) o[c] = f2b(Ls[(wg * 8 + c) * 65 + nl]);
        uint4 ou;
        ou.x = (unsigned)o[0] | ((unsigned)o[1] << 16);
        ou.y = (unsigned)o[2] | ((unsigned)o[3] << 16);
        ou.z = (unsigned)o[4] | ((unsigned)o[5] << 16);
        ou.w = (unsigned)o[6] | ((unsigned)o[7] << 16);
        *(uint4*)(dst + (size_t)(nb + nl) * 256 + kb + wg * 8) = ou;
    }
}

// ---------- stage 1 (fp32): LN + FFN + rot + argmax with top-2 margin ----------
__global__ __launch_bounds__(256) void k_stage1(
    const float* __restrict__ x, const float* __restrict__ g, const float* __restrict__ be,
    const float* __restrict__ w1, const float* __restrict__ b1,
    const float* __restrict__ w2, const float* __restrict__ b2,
    const float* __restrict__ rot, const int* __restrict__ mski,
    ushort* __restrict__ xn_out, float* __restrict__ xd_out, int* __restrict__ bin_out,
    int* __restrict__ fixlist, int* __restrict__ fixcnt)
{
    __shared__ float xs[16][257];
    __shared__ float hs[16][129];
    int tid = threadIdx.x;
    int base = blockIdx.x * 16;

    {   // phase 0: load + layernorm
        int pl = tid >> 4, t = tid & 15;
        int pt = base + pl;
        const float* xr = x + (size_t)pt * FF;
        float s = 0.f;
        for (int i = t; i < FF; i += 16) { float v = xr[i]; xs[pl][i] = v; s += v; }
        for (int off = 1; off < 16; off <<= 1) s += __shfl_xor(s, off, 16);
        float mu = s * (1.f / 256.f);
        float s2 = 0.f;
        for (int i = t; i < FF; i += 16) { float d = xs[pl][i] - mu; s2 += d * d; }
        for (int off = 1; off < 16; off <<= 1) s2 += __shfl_xor(s2, off, 16);
        float rs = 1.0f / sqrtf(s2 * (1.f / 256.f) + 1e-6f);
        ushort* xo = xn_out + (size_t)pt * FF;
        for (int i = t; i < FF; i += 16) {
            float v = (xs[pl][i] - mu) * rs * g[i] + be[i];
            xs[pl][i] = v;
            xo[i] = f2b(v);
        }
    }
    __syncthreads();
    {   // phase 1: h = elu(xn @ w1 + b1); thread = 4 rows x 2 cols
        int rg = tid >> 6, ct = tid & 63;
        float acc[4][2];
        float bA = b1[ct], bBv = b1[ct + 64];
        #pragma unroll
        for (int rr = 0; rr < 4; rr++) { acc[rr][0] = bA; acc[rr][1] = bBv; }
        #pragma unroll 4
        for (int k = 0; k < FF; k++) {
            float w0 = w1[k * DDIM + ct];
            float wA = w1[k * DDIM + ct + 64];
            #pragma unroll
            for (int rr = 0; rr < 4; rr++) {
                float a = xs[rg * 4 + rr][k];
                acc[rr][0] = fmaf(a, w0, acc[rr][0]);
                acc[rr][1] = fmaf(a, wA, acc[rr][1]);
            }
        }
        #pragma unroll
        for (int rr = 0; rr < 4; rr++) {
            float h0 = acc[rr][0], h1 = acc[rr][1];
            hs[rg * 4 + rr][ct]      = (h0 > 0.f) ? h0 : expm1f(h0);
            hs[rg * 4 + rr][ct + 64] = (h1 > 0.f) ? h1 : expm1f(h1);
        }
    }
    __syncthreads();
    {   // phase 2: xd = h @ w2 + b2 -> xs[p][0..127] and global
        int rg = tid >> 6, ct = tid & 63;
        float acc[4][2];
        float bA = b2[ct], bBv = b2[ct + 64];
        #pragma unroll
        for (int rr = 0; rr < 4; rr++) { acc[rr][0] = bA; acc[rr][1] = bBv; }
        #pragma unroll 4
        for (int k = 0; k < DDIM; k++) {
            float w0 = w2[k * DDIM + ct];
            float wA = w2[k * DDIM + ct + 64];
            #pragma unroll
            for (int rr = 0; rr < 4; rr++) {
                float a = hs[rg * 4 + rr][k];
                acc[rr][0] = fmaf(a, w0, acc[rr][0]);
                acc[rr][1] = fmaf(a, wA, acc[rr][1]);
            }
        }
        #pragma unroll
        for (int rr = 0; rr < 4; rr++) {
            int p = rg * 4 + rr;
            xs[p][ct]      = acc[rr][0];
            xs[p][ct + 64] = acc[rr][1];
            xd_out[(size_t)(base + p) * DDIM + ct]      = acc[rr][0];
            xd_out[(size_t)(base + p) * DDIM + ct + 64] = acc[rr][1];
        }
    }
    __syncthreads();
    {   // phase 3: mul = xd @ rot[:, :50]; top-2 argmax over [mul, -mul]
        int wv = tid >> 6, c = tid & 63;
        for (int r = 0; r < 4; r++) {
            int p = wv * 4 + r;
            float v1, v2 = -1e30f; int i1;
            if (c < NROT) {
                float m = 0.f;
                #pragma unroll 4
                for (int k = 0; k < DDIM; k++) m = fmaf(xs[p][k], rot[k * 100 + c], m);
                if (m >= 0.f) { v1 = m; i1 = c; } else { v1 = -m; i1 = 50 + c; }
            } else { v1 = -1e30f; i1 = 1 << 29; }
            #pragma unroll
            for (int off = 1; off < 64; off <<= 1) {
                float o1 = __shfl_xor(v1, off, 64);
                int   oi = __shfl_xor(i1, off, 64);
                float o2 = __shfl_xor(v2, off, 64);
                bool take = (o1 > v1) || (o1 == v1 && oi < i1);
                float loser = take ? v1 : o1;
                if (take) { v1 = o1; i1 = oi; }
                v2 = fmaxf(fmaxf(v2, o2), loser);
            }
            if (c == 0) {
                int pt = base + p;
                bin_out[pt] = i1 + (mski[pt] ? 0 : (NBINS - 1));
                float tau = 2e-4f + 1e-3f * v1;
                if (v1 - v2 < tau) {
                    int pos = atomicAdd(fixcnt, 1);
                    fixlist[pos] = pt;
                }
            }
        }
    }
}

// ---------- fp64 fixup for margin-flagged points (one wave per point) ----------
__global__ __launch_bounds__(64) void k_fixup(
    const float* __restrict__ x, const float* __restrict__ g, const float* __restrict__ be,
    const float* __restrict__ w1, const float* __restrict__ b1,
    const float* __restrict__ w2, const float* __restrict__ b2,
    const float* __restrict__ rot, const int* __restrict__ mski,
    const int* __restrict__ fixlist, const int* __restrict__ fixcnt,
    int* __restrict__ bin_out)
{
    __shared__ double xn_s[256];
    __shared__ double h_s[128];
    __shared__ double xd_s[128];
    int lane = threadIdx.x;
    int n = fixcnt[0];
    for (int e = blockIdx.x; e < n; e += gridDim.x) {
        int pt = fixlist[e];
        const float* xr = x + (size_t)pt * FF;
        double s = 0.0, xv[4];
        #pragma unroll
        for (int q = 0; q < 4; q++) { xv[q] = (double)xr[lane + q * 64]; s += xv[q]; }
        #pragma unroll
        for (int off = 1; off < 64; off <<= 1) s += __shfl_xor(s, off, 64);
        double mu = s * (1.0 / 256.0);
        double s2 = 0.0;
        #pragma unroll
        for (int q = 0; q < 4; q++) { double d = xv[q] - mu; s2 += d * d; }
        #pragma unroll
        for (int off = 1; off < 64; off <<= 1) s2 += __shfl_xor(s2, off, 64);
        double rs = 1.0 / sqrt(s2 * (1.0 / 256.0) + 1e-6);
        #pragma unroll
        for (int q = 0; q < 4; q++) {
            int i = lane + q * 64;
            xn_s[i] = (xv[q] - mu) * rs * (double)g[i] + (double)be[i];
        }
        __syncthreads();
        #pragma unroll
        for (int q = 0; q < 2; q++) {
            int j = lane + q * 64;
            double a = (double)b1[j];
            for (int k = 0; k < FF; k++) a += xn_s[k] * (double)w1[k * DDIM + j];
            h_s[j] = (a > 0.0) ? a : expm1(a);
        }
        __syncthreads();
        #pragma unroll
        for (int q = 0; q < 2; q++) {
            int j = lane + q * 64;
            double a = (double)b2[j];
            for (int k = 0; k < DDIM; k++) a += h_s[k] * (double)w2[k * DDIM + j];
            xd_s[j] = a;
        }
        __syncthreads();
        double v; int idx;
        if (lane < NROT) {
            double m = 0.0;
            for (int k = 0; k < DDIM; k++) m += xd_s[k] * (double)rot[k * 100 + lane];
            if (m >= 0.0) { v = m; idx = lane; } else { v = -m; idx = 50 + lane; }
        } else { v = -1e300; idx = 1 << 29; }
        #pragma unroll
        for (int off = 1; off < 64; off <<= 1) {
            double ov = __shfl_xor(v, off, 64);
            int oi = __shfl_xor(idx, off, 64);
            if (ov > v || (ov == v && oi < idx)) { v = ov; idx = oi; }
        }
        if (lane == 0) bin_out[pt] = idx + (mski[pt] ? 0 : (NBINS - 1));
        __syncthreads();
    }
}

// ---------- binning: stable counting sort ----------
__global__ void k_count(const int* __restrict__ bin, int* __restrict__ hist) {
    int c = blockIdx.x % 100, b = blockIdx.x / 100;
    int t = threadIdx.x;
    int v = bin[b * NN + c * BSIZE + t];
    atomicAdd(&hist[(b * 100 + c) * NIDS + v], 1);
}

__global__ void k_offsets(const int* __restrict__ hist, int* __restrict__ offs) {
    __shared__ int tot[NIDS];
    __shared__ int start[NIDS];
    int b = blockIdx.x, v = threadIdx.x;
    if (v < NIDS) {
        int s = 0;
        for (int c = 0; c < 100; c++) s += hist[(b * 100 + c) * NIDS + v];
        tot[v] = s;
    }
    __syncthreads();
    if (threadIdx.x == 0) {
        int run = 0;
        for (int i = 0; i < NIDS; i++) { start[i] = run; run += tot[i]; }
    }
    __syncthreads();
    if (v < NIDS) {
        int run = start[v];
        for (int c = 0; c < 100; c++) {
            offs[(b * 100 + c) * NIDS + v] = run;
            run += hist[(b * 100 + c) * NIDS + v];
        }
    }
}

__global__ void k_scatter(const int* __restrict__ bin, const int* __restrict__ offs,
                          const int* __restrict__ mski, int* __restrict__ flat,
                          float* __restrict__ mf) {
    __shared__ int sv[BSIZE];
    int c = blockIdx.x % 100, b = blockIdx.x / 100;
    int t = threadIdx.x;
    int n = c * BSIZE + t;
    int v = bin[b * NN + n];
    sv[t] = v;
    __syncthreads();
    int rank = 0;
    for (int u = 0; u < t; u++) rank += (sv[u] == v);
    int r = offs[(b * 100 + c) * NIDS + v] + rank;
    flat[b * NN + r] = b * NN + n;
    mf[b * NN + r] = mski[b * NN + n] ? 1.0f : 0.0f;
}

// ---------- per-bin pairwise kernel matrix (fp32 tiled), fused deg/norm ----------
__global__ __launch_bounds__(256) void k_dm(const float* __restrict__ xd, const int* __restrict__ flat,
                                            const float* __restrict__ mf, ushort* __restrict__ dmb,
                                            float* __restrict__ norm) {
    __shared__ float Xs[128 * 64];
    __shared__ float na[128];
    __shared__ float ml[128];
    __shared__ float ps[128 * 16];
    int g = blockIdx.x, tid = threadIdx.x;
    int tx = tid & 15, ty = tid >> 4;
    int rowbase = g * 128;
    if (tid < 128) ml[tid] = mf[rowbase + tid];
    float acc[8][8];
    #pragma unroll
    for (int i = 0; i < 8; i++)
        #pragma unroll
        for (int j = 0; j < 8; j++) acc[i][j] = 0.f;
    float nap[8];
    #pragma unroll
    for (int j = 0; j < 8; j++) nap[j] = 0.f;

    for (int kh = 0; kh < 2; ++kh) {
        __syncthreads();
        for (int q = 0; q < 8; ++q) {
            int gg = q * 256 + tid;
            int row = gg >> 4, f4 = gg & 15;
            int srow = flat[rowbase + row];
            float4 v = *(const float4*)(xd + (size_t)srow * DDIM + kh * 64 + f4 * 4);
            int f4s = f4 ^ ((row >> 3) & 7);
            *(float4*)(Xs + row * 64 + f4s * 4) = v;
        }
        __syncthreads();
        for (int k4 = 0; k4 < 16; ++k4) {
            int sa = (k4 ^ (ty & 7)) << 2;
            int sb = (k4 ^ (tx & 7)) << 2;
            float4 av[8], bv[8];
            #pragma unroll
            for (int i = 0; i < 8; i++) av[i] = *(const float4*)(Xs + (ty * 8 + i) * 64 + sa);
            #pragma unroll
            for (int j = 0; j < 8; j++) bv[j] = *(const float4*)(Xs + (tx * 8 + j) * 64 + sb);
            if (ty == 0) {
                #pragma unroll
                for (int j = 0; j < 8; j++)
                    nap[j] += bv[j].x * bv[j].x + bv[j].y * bv[j].y + bv[j].z * bv[j].z + bv[j].w * bv[j].w;
            }
            #pragma unroll
            for (int i = 0; i < 8; i++)
                #pragma unroll
                for (int j = 0; j < 8; j++)
                    acc[i][j] += av[i].x * bv[j].x + av[i].y * bv[j].y + av[i].z * bv[j].z + av[i].w * bv[j].w;
        }
    }
    if (ty == 0) {
        #pragma unroll
        for (int j = 0; j < 8; j++) na[tx * 8 + j] = nap[j];
    }
    __syncthreads();
    #pragma unroll
    for (int i = 0; i < 8; ++i) {
        int r = ty * 8 + i;
        float nai = na[r], mi = ml[r];
        float rs = 0.f;
        ushort o[8];
        #pragma unroll
        for (int j = 0; j < 8; ++j) {
            int c = tx * 8 + j;
            float D2 = nai - 2.f * acc[i][j] + na[c];
            float dv = expf(-0.1f * sqrtf(fmaxf(D2, 1e-6f)));
            dv *= mi * ml[c];
            rs += dv;
            o[j] = f2b(dv);
        }
        uint4 ou;
        ou.x = (unsigned)o[0] | ((unsigned)o[1] << 16);
        ou.y = (unsigned)o[2] | ((unsigned)o[3] << 16);
        ou.z = (unsigned)o[4] | ((unsigned)o[5] << 16);
        ou.w = (unsigned)o[6] | ((unsigned)o[7] << 16);
        *(uint4*)(dmb + (size_t)g * 16384 + r * 128 + tx * 8) = ou;
        ps[r * 16 + tx] = rs;
    }
    __syncthreads();
    if (tid < 128) {
        float deg = 0.f;
        for (int t2 = 0; t2 < 16; ++t2) deg += ps[tid * 16 + t2];
        deg = fminf(deg, 1000.0f);
        float nv = 1.0f / sqrtf(deg + 1e-6f);
        norm[rowbase + tid] = nv * ml[tid];
    }
}

// ---------- MFMA helpers ----------
__device__ __forceinline__ void stage_bf16(const ushort* __restrict__ src, size_t pitch,
                                           const int* __restrict__ rowmap, int rowbase, size_t kbase,
                                           ushort* lds, int nrows, int tid, int nthr) {
    int total = nrows * 8;
    for (int g = tid; g < total; g += nthr) {
        int row = g >> 3, wg = g & 7;
        size_t srow = rowmap ? (size_t)rowmap[rowbase + row] : (size_t)(rowbase + row);
        uint4 v = *(const uint4*)(src + srow * pitch + kbase + wg * 8);
        int w0 = (wg * 4) ^ ((row & 7) << 2);
        *(uint4*)((char*)lds + row * 128 + w0 * 4) = v;
    }
}

__device__ __forceinline__ short8 frag_ld(const ushort* lds, int row, int kc, int lane) {
    int w0 = (kc * 16 + ((lane >> 4) << 2)) ^ ((row & 7) << 2);
    return *(const short8*)((const char*)lds + row * 128 + w0 * 4);
}

// ---------- T = (A @ W) * norm, stored transposed bf16 [c][row] ----------
__global__ __launch_bounds__(256) void k_proj(const ushort* __restrict__ A, const int* __restrict__ rowmap,
                                              const ushort* __restrict__ Wt, const float* __restrict__ norm,
                                              ushort* __restrict__ Tt) {
    __shared__ ushort lA[128 * 64];
    __shared__ ushort lB[128 * 64];
    int tid = threadIdx.x, lane = tid & 63, wid = tid >> 6;
    int rowbase = blockIdx.x * 128, nbase = blockIdx.y * 128;
    int wm = (wid >> 1) * 64, wn = (wid & 1) * 64;
    int l15 = lane & 15;
    floatx4 zf = {0.f, 0.f, 0.f, 0.f};
    floatx4 acc[4][4];
    #pragma unroll
    for (int m = 0; m < 4; m++)
        #pragma unroll
        for (int n = 0; n < 4; n++) acc[m][n] = zf;
    for (int kb = 0; kb < 4; ++kb) {
        __syncthreads();
        stage_bf16(A, 256, rowmap, rowbase, (size_t)kb * 64, lA, 128, tid, 256);
        stage_bf16(Wt, 256, nullptr, nbase, (size_t)kb * 64, lB, 128, tid, 256);
        __syncthreads();
        #pragma unroll
        for (int kc = 0; kc < 2; ++kc) {
            short8 a[4], b[4];
            #pragma unroll
            for (int m = 0; m < 4; m++) a[m] = frag_ld(lA, wm + m * 16 + l15, kc, lane);
            #pragma unroll
            for (int n = 0; n < 4; n++) b[n] = frag_ld(lB, wn + n * 16 + l15, kc, lane);
            #pragma unroll
            for (int m = 0; m < 4; m++)
                #pragma unroll
                for (int n = 0; n < 4; n++)
                    acc[m][n] = __builtin_amdgcn_mfma_f32_16x16x32_bf16(a[m], b[n], acc[m][n], 0, 0, 0);
        }
    }
    int r4 = (lane >> 4) * 4;
    #pragma unroll
    for (int m = 0; m < 4; m++) {
        int r0 = rowbase + wm + m * 16 + r4;
        float4 nv = *(const float4*)(norm + r0);
        #pragma unroll
        for (int n = 0; n < 4; n++) {
            int cg = nbase + wn + n * 16 + l15;
            ushort4 o;
            o.x = f2b(acc[m][n][0] * nv.x);
            o.y = f2b(acc[m][n][1] * nv.y);
            o.z = f2b(acc[m][n][2] * nv.z);
            o.w = f2b(acc[m][n][3] * nv.w);
            *(ushort4*)(Tt + (size_t)cg * PITCH_T + r0) = o;
        }
    }
}

// ---------- FH = (dm @ T) * norm, stored transposed fp32 [c][row] ----------
__global__ __launch_bounds__(512) void k_adj(const ushort* __restrict__ dmb, const ushort* __restrict__ Tt,
                                             const float* __restrict__ norm, float* __restrict__ FHt) {
    __shared__ ushort lA[128 * 64];
    __shared__ ushort lB[256 * 64];
    int g = blockIdx.x;
    int tid = threadIdx.x, lane = tid & 63, wid = tid >> 6;
    int wm = (wid >> 2) * 64, wn = (wid & 3) * 64;
    int l15 = lane & 15;
    const ushort* dmg = dmb + (size_t)g * 16384;
    floatx4 zf = {0.f, 0.f, 0.f, 0.f};
    floatx4 acc[4][4];
    #pragma unroll
    for (int m = 0; m < 4; m++)
        #pragma unroll
        for (int n = 0; n < 4; n++) acc[m][n] = zf;
    for (int kb = 0; kb < 2; ++kb) {
        __syncthreads();
        stage_bf16(dmg, 128, nullptr, 0, (size_t)kb * 64, lA, 128, tid, 512);
        stage_bf16(Tt, PITCH_T, nullptr, 0, (size_t)g * 128 + kb * 64, lB, 256, tid, 512);
        __syncthreads();
        #pragma unroll
        for (int kc = 0; kc < 2; ++kc) {
            short8 a[4], b[4];
            #pragma unroll
            for (int m = 0; m < 4; m++) a[m] = frag_ld(lA, wm + m * 16 + l15, kc, lane);
            #pragma unroll
            for (int n = 0; n < 4; n++) b[n] = frag_ld(lB, wn + n * 16 + l15, kc, lane);
            #pragma unroll
            for (int m = 0; m < 4; m++)
                #pragma unroll
                for (int n = 0; n < 4; n++)
                    acc[m][n] = __builtin_amdgcn_mfma_f32_16x16x32_bf16(a[m], b[n], acc[m][n], 0, 0, 0);
        }
    }
    int r4 = (lane >> 4) * 4;
    #pragma unroll
    for (int m = 0; m < 4; m++) {
        int r0l = wm + m * 16 + r4;
        float4 nv = *(const float4*)(norm + g * 128 + r0l);
        #pragma unroll
        for (int n = 0; n < 4; n++) {
            int cg = wn + n * 16 + l15;
            float4 o;
            o.x = acc[m][n][0] * nv.x;
            o.y = acc[m][n][1] * nv.y;
            o.z = acc[m][n][2] * nv.z;
            o.w = acc[m][n][3] * nv.w;
            *(float4*)(FHt + (size_t)cg * PITCH_T + g * 128 + r0l) = o;
        }
    }
}

// ---------- combine: dual GEMM (wh, wt) + gate/elu epilogue ----------
template<int LAYER>
__global__ __launch_bounds__(512) void k_comb(const ushort* __restrict__ A, const int* __restrict__ rowmap,
                                              const ushort* __restrict__ WhT, const ushort* __restrict__ WtT,
                                              const float* __restrict__ bt, const float* __restrict__ FHt,
                                              const float* __restrict__ mf,
                                              ushort* __restrict__ outb, float* __restrict__ outf,
                                              const int* __restrict__ flatscat) {
    __shared__ ushort lA[128 * 64];
    __shared__ ushort lH[128 * 64];
    __shared__ ushort lG[128 * 64];
    int tid = threadIdx.x, lane = tid & 63, wid = tid >> 6;
    int rowbase = blockIdx.x * 128, nbase = blockIdx.y * 128;
    int wm = (wid >> 2) * 64, wn = (wid & 3) * 32;
    int l15 = lane & 15;
    floatx4 zf = {0.f, 0.f, 0.f, 0.f};
    floatx4 accH[4][2], accG[4][2];
    #pragma unroll
    for (int m = 0; m < 4; m++)
        #pragma unroll
        for (int n = 0; n < 2; n++) { accH[m][n] = zf; accG[m][n] = zf; }
    for (int kb = 0; kb < 4; ++kb) {
        __syncthreads();
        stage_bf16(A, 256, rowmap, rowbase, (size_t)kb * 64, lA, 128, tid, 512);
        stage_bf16(WhT, 256, nullptr, nbase, (size_t)kb * 64, lH, 128, tid, 512);
        stage_bf16(WtT, 256, nullptr, nbase, (size_t)kb * 64, lG, 128, tid, 512);
        __syncthreads();
        #pragma unroll
        for (int kc = 0; kc < 2; ++kc) {
            short8 a[4], bh[2], bg[2];
            #pragma unroll
            for (int m = 0; m < 4; m++) a[m] = frag_ld(lA, wm + m * 16 + l15, kc, lane);
            #pragma unroll
            for (int n = 0; n < 2; n++) {
                bh[n] = frag_ld(lH, wn + n * 16 + l15, kc, lane);
                bg[n] = frag_ld(lG, wn + n * 16 + l15, kc, lane);
            }
            #pragma unroll
            for (int m = 0; m < 4; m++)
                #pragma unroll
                for (int n = 0; n < 2; n++) {
                    accH[m][n] = __builtin_amdgcn_mfma_f32_16x16x32_bf16(a[m], bh[n], accH[m][n], 0, 0, 0);
                    accG[m][n] = __builtin_amdgcn_mfma_f32_16x16x32_bf16(a[m], bg[n], accG[m][n], 0, 0, 0);
                }
        }
    }
    int r4 = (lane >> 4) * 4;
    int base = wid * 512;
    for (int m = 0; m < 4; m++) {
        int r0l = wm + m * 16 + r4;
        int r0g = rowbase + r0l;
        float4 mv = *(const float4*)(mf + r0g);
        float mvv[4] = {mv.x, mv.y, mv.z, mv.w};
        float vals[2][4];
        #pragma unroll
        for (int n = 0; n < 2; n++) {
            int cg = nbase + wn + n * 16 + l15;
            float btc = bt[cg];
            float4 fh = *(const float4*)(FHt + (size_t)cg * PITCH_T + r0g);
            float fhv[4] = {fh.x, fh.y, fh.z, fh.w};
            #pragma unroll
            for (int i = 0; i < 4; i++) {
                float gate = 1.f / (1.f + expf(-(accG[m][n][i] + btc)));
                float het = mvv[i] * accH[m][n][i];
                float o = gate * fhv[i] + (1.f - gate) * het;
                o = (o > 0.f) ? o : expm1f(o);
                vals[n][i] = o * mvv[i];
            }
        }
        __syncthreads();
        if (LAYER == 0) {
            ushort* Ls = lA;
            #pragma unroll
            for (int n = 0; n < 2; n++)
                #pragma unroll
                for (int i = 0; i < 4; i++)
                    Ls[base + (r4 + i) * 32 + n * 16 + l15] = f2b(vals[n][i]);
            __syncthreads();
            #pragma unroll
            for (int it = 0; it < 2; ++it) {
                int lr = (lane >> 3) + it * 8;
                int lc4 = (lane & 7) * 4;
                ushort4 tv = *(const ushort4*)(Ls + base + lr * 32 + lc4);
                int rg = rowbase + wm + m * 16 + lr;
                *(ushort4*)(outb + (size_t)rg * 256 + nbase + wn + lc4) = tv;
            }
        } else {
            float* Ls = (float*)lA;
            #pragma unroll
            for (int n = 0; n < 2; n++)
                #pragma unroll
                for (int i = 0; i < 4; i++)
                    Ls[base + (r4 + i) * 32 + n * 16 + l15] = vals[n][i];
            __syncthreads();
            #pragma unroll
            for (int it = 0; it < 2; ++it) {
                int lr = (lane >> 3) + it * 8;
                int lc4 = (lane & 7) * 4;
                float4 tv = *(const float4*)(Ls + base + lr * 32 + lc4);
                int rg = rowbase + wm + m * 16 + lr;
                int dst = flatscat[rg];
                *(float4*)(outf + (size_t)dst * 256 + nbase + wn + lc4) = tv;
            }
        }
    }
}

extern "C" void kernel_launch(void* const* d_in, const int* in_sizes, int n_in,
                              void* d_out, int out_size, void* d_ws, size_t ws_size,
                              hipStream_t stream) {
    const float* x    = (const float*)d_in[0];
    const void*  msk  = d_in[1];
    const float* ln_g = (const float*)d_in[2];
    const float* ln_b = (const float*)d_in[3];
    const float* w1   = (const float*)d_in[4];
    const float* b1   = (const float*)d_in[5];
    const float* w2   = (const float*)d_in[6];
    const float* b2   = (const float*)d_in[7];
    const float* rot  = (const float*)d_in[8];
    const float* th0  = (const float*)d_in[9];
    const float* wh0  = (const float*)d_in[10];
    const float* wt0  = (const float*)d_in[11];
    const float* bt0  = (const float*)d_in[12];
    const float* th1  = (const float*)d_in[13];
    const float* wh1  = (const float*)d_in[14];
    const float* wt1  = (const float*)d_in[15];
    const float* bt1  = (const float*)d_in[16];

    char* ws = (char*)d_ws;
    float*  FHt  = (float*)(ws + OFF_FHT);
    ushort* Tt   = (ushort*)(ws + OFF_TT);
    ushort* out0 = (ushort*)(ws + OFF_OUT0);
    ushort* dmb  = (ushort*)(ws + OFF_DMB);
    ushort* wb   = (ushort*)(ws + OFF_WB);
    ushort* wbth0 = wb + 0 * 65536;
    ushort* wbwh0 = wb + 1 * 65536;
    ushort* wbwt0 = wb + 2 * 65536;
    ushort* wbth1 = wb + 3 * 65536;
    ushort* wbwh1 = wb + 4 * 65536;
    ushort* wbwt1 = wb + 5 * 65536;
    float* norm = (float*)(ws + OFF_NORM);
    float* mf   = (float*)(ws + OFF_MF);
    int*   bin  = (int*)(ws + OFF_BIN);
    int*   flat = (int*)(ws + OFF_FLAT);
    int*   mski = (int*)(ws + OFF_MSKI);
    int*   hist = (int*)(ws + OFF_HIST);
    int*   offs = (int*)(ws + OFF_OFFS);
    int*   flag = (int*)(ws + OFF_FLAG);
    int*   fixcnt = (int*)(ws + OFF_CNT);
    int*   fixlist = (int*)(ws + OFF_LIST);
    float*  xd  = (float*)d_out;
    ushort* xnb = (ushort*)((char*)d_out + (size_t)PTS * DDIM * 4);

    hipMemsetAsync(hist, 0, HISTBYTES, stream);
    hipMemsetAsync(fixcnt, 0, 4, stream);
    k_maskflag<<<1, 256, 0, stream>>>((const int*)msk, flag);
    k_masknorm<<<PTS / 256, 256, 0, stream>>>(msk, flag, mski);
    k_wprep<<<dim3(16, 6), 256, 0, stream>>>(th0, wh0, wt0, th1, wh1, wt1,
                                             wbth0, wbwh0, wbwt0, wbth1, wbwh1, wbwt1);
    k_stage1<<<PTS / 16, 256, 0, stream>>>(x, ln_g, ln_b, w1, b1, w2, b2, rot, mski,
                                           xnb, xd, bin, fixlist, fixcnt);
    k_fixup<<<2048, 64, 0, stream>>>(x, ln_g, ln_b, w1, b1, w2, b2, rot, mski,
                                     fixlist, fixcnt, bin);
    k_count<<<800, 128, 0, stream>>>(bin, hist);
    k_offsets<<<8, 256, 0, stream>>>(hist, offs);
    k_scatter<<<800, 128, 0, stream>>>(bin, offs, mski, flat, mf);
    k_dm<<<800, 256, 0, stream>>>(xd, flat, mf, dmb, norm);
    // layer 0
    k_proj<<<dim3(800, 2), 256, 0, stream>>>(xnb, flat, wbth0, norm, Tt);
    k_adj<<<800, 512, 0, stream>>>(dmb, Tt, norm, FHt);
    k_comb<0><<<dim3(800, 2), 512, 0, stream>>>(xnb, flat, wbwh0, wbwt0, bt0, FHt, mf, out0, nullptr, nullptr);
    // layer 1
    k_proj<<<dim3(800, 2), 256, 0, stream>>>(out0, nullptr, wbth1, norm, Tt);
    k_adj<<<800, 512, 0, stream>>>(dmb, Tt, norm, FHt);
    k_comb<1><<<dim3(800, 2), 512, 0, stream>>>(out0, nullptr, wbwh1, wbwt1, bt1, FHt, mf, nullptr, (float*)d_out, flat);
}